// Round 14
// baseline (175.598 us; speedup 1.0000x reference)
//
#include <hip/hip_runtime.h>
#include <hip/hip_bf16.h>
#include <math.h>

#define BLK 64
#define EPB 16            // elements per block (one wave)
#define NF 32
#define THIST 15

typedef __attribute__((ext_vector_type(8))) short s16x8;  // 8 bf16 = 4 VGPRs
typedef __attribute__((ext_vector_type(4))) float f32x4;
typedef __attribute__((ext_vector_type(2))) float f32x2;  // -> v_pk_* f32 ops

union frag_u { s16x8 v; unsigned u[4]; };

__device__ __forceinline__ float frcp(float x) {
    return __builtin_amdgcn_rcpf(x);
}
// raw v_exp_f32 via COMPILER BUILTIN (hazards handled; no OCML fixup).
__device__ __forceinline__ float exp2b(float x) {
    return __builtin_amdgcn_exp2f(x);
}
__device__ __forceinline__ unsigned packbf2(float x0, float x1) {
    __hip_bfloat162 b = __float22bfloat162_rn(float2{x0, x1});
    union { __hip_bfloat162 b; unsigned u; } c; c.b = b; return c.u;
}
// tanh for the uniform Riccati prologue only
__device__ __forceinline__ float tanhfe(float x) {
    float e = __expf(2.0f * x);
    return fmaf(-2.0f, frcp(e + 1.0f), 1.0f);
}

// P = F P F^T for the constant-accel F (dt=0.2), in place (uniform Riccati only)
__device__ __forceinline__ void fpft(float (&P)[6][6]) {
    const float dt = 0.2f, hd = 0.02f;
    #pragma unroll
    for (int j = 0; j < 6; ++j) {
        float a0 = P[0][j] + dt * P[1][j] + hd * P[2][j];
        float a1 = P[1][j] + dt * P[2][j];
        float a3 = P[3][j] + dt * P[4][j] + hd * P[5][j];
        float a4 = P[4][j] + dt * P[5][j];
        P[0][j] = a0; P[1][j] = a1; P[3][j] = a3; P[4][j] = a4;
    }
    #pragma unroll
    for (int i = 0; i < 6; ++i) {
        float a0 = P[i][0] + dt * P[i][1] + hd * P[i][2];
        float a1 = P[i][1] + dt * P[i][2];
        float a3 = P[i][3] + dt * P[i][4] + hd * P[i][5];
        float a4 = P[i][4] + dt * P[i][5];
        P[i][0] = a0; P[i][1] = a1; P[i][3] = a3; P[i][4] = a4;
    }
}

// ------------------------------- main kernel ---------------------------------
// R14 = R13 software-pipelined by hand (BIT-IDENTICAL arithmetic, reorder only):
//  - lstm_step split into compute_feat / lstm_core.
//  - HISTORY: feat(X_{t+1}) computed inside iteration t (after lstm_core) —
//    its MFMA+trans chain overlaps combine's stalls; step t+1 starts directly
//    at gates-MFMA. (feat depends only on X, not on h — scheduler can't do
//    this across the unroll-1 back edge on its own.)
//  - PRED: P-update + output rotated by one iteration (carry cmdSv/XoutSv) so
//    their ~150cy VALU/sqrt tail overlaps the NEXT step's trans front-end.
// R13 miss lesson recorded: packed math only pays on pure-FMA chains; trans
// extraction overhead eats it elsewhere.
__global__ __launch_bounds__(BLK, 2)
void kalman_lstm(const float* __restrict__ hist,
                 const float* __restrict__ psx, const float* __restrict__ psy,
                 const float* __restrict__ vsx, const float* __restrict__ vsy,
                 const float* __restrict__ asx, const float* __restrict__ asy,
                 const float* __restrict__ jerk, const float* __restrict__ coefG,
                 const float* __restrict__ GRv,
                 const float* __restrict__ cfW, const float* __restrict__ cfb,
                 const float* __restrict__ Wih, const float* __restrict__ Whh,
                 const float* __restrict__ bih, const float* __restrict__ bhh,
                 const float* __restrict__ coW, const float* __restrict__ cob,
                 float* __restrict__ out, int B, int len_pred)
{
    __shared__ float kf[216];  // [t*12..+11]=K pairs (paired layout); [180..215]=P_hist

    const int lane = threadIdx.x;
    const int e = lane & 15;              // element slot (MFMA n-index / D col)
    const int s = lane >> 4;              // quad (k-slice / D row group)
    const int b = blockIdx.x * EPB + e;

    const float dt = 0.2f, hd = 0.02f;
    const float g0 = dt * dt * dt / 6.0f, g1 = 0.02f, g2 = dt;
    const float NL2E  = -1.4426950408889634f;   // -log2(e)
    const float T2L2E =  2.8853900817779268f;   // 2*log2(e)
    float ga0 = g0 * tanhf(coefG[0]);
    float ga1 = g1 * tanhf(coefG[1]);
    float ga2 = g2 * tanhf(coefG[2]);
    float gb3 = g0 * tanhf(coefG[3]);
    float gb4 = g1 * tanhf(coefG[4]);
    float gb5 = g2 * tanhf(coefG[5]);

    // ---- batch-uniform Kalman-gain recursion (verbatim math; lane0 writes) ----
    // K stored PAIRED for packed consumption:
    //  t*12: {K0[0],K0[3], K0[1],K0[4], K0[2],K0[5], K1[0],K1[3], K1[1],K1[4], K1[2],K1[5]}
    {
        float j0 = jerk[0], j1 = jerk[1];
        float gr0 = GRv[0], gr1 = GRv[1];
        float R00 = gr0 * gr0, R01 = gr0 * gr1, R11 = gr1 * gr1;
        float qa[3] = {ga0 * j0, ga1 * j0, ga2 * j0};
        float qb[3] = {gb3 * j1, gb4 * j1, gb5 * j1};

        float Pk[6][6];
        #pragma unroll
        for (int i = 0; i < 6; ++i)
            #pragma unroll
            for (int j = 0; j < 6; ++j) Pk[i][j] = 0.0f;
        { float v;
          v = psx[0]; Pk[0][0] = v * v;
          v = vsx[0]; Pk[1][1] = v * v;
          v = asx[0]; Pk[2][2] = v * v;
          v = psy[0]; Pk[3][3] = v * v;
          v = vsy[0]; Pk[4][4] = v * v;
          v = asy[0]; Pk[5][5] = v * v; }

        #pragma unroll 1
        for (int t = 0; t < THIST; ++t) {
            fpft(Pk);
            #pragma unroll
            for (int i = 0; i < 3; ++i)
                #pragma unroll
                for (int j = 0; j < 3; ++j) {
                    Pk[i][j]         += qa[i] * qa[j];
                    Pk[3 + i][3 + j] += qb[i] * qb[j];
                }
            float S00 = Pk[0][0] + R00;
            float S01 = Pk[0][3] + R01;
            float S11 = Pk[3][3] + R11;
            float idet = 1.0f / (S00 * S11 - S01 * S01);
            float i00 =  S11 * idet, i01 = -S01 * idet, i11 = S00 * idet;
            float K0[6], K1[6];
            #pragma unroll
            for (int i = 0; i < 6; ++i) {
                K0[i] = Pk[i][0] * i00 + Pk[i][3] * i01;
                K1[i] = Pk[i][0] * i01 + Pk[i][3] * i11;
            }
            if (lane == 0) {
                #pragma unroll
                for (int i = 0; i < 3; ++i) {
                    kf[t * 12 + 2 * i]     = K0[i];
                    kf[t * 12 + 2 * i + 1] = K0[3 + i];
                    kf[t * 12 + 6 + 2 * i]     = K1[i];
                    kf[t * 12 + 6 + 2 * i + 1] = K1[3 + i];
                }
            }
            #pragma unroll
            for (int i = 0; i < 6; ++i) {
                Pk[i][1] -= K0[1] * Pk[i][0] + K1[1] * Pk[i][3];
                Pk[i][2] -= K0[2] * Pk[i][0] + K1[2] * Pk[i][3];
                Pk[i][4] -= K0[4] * Pk[i][0] + K1[4] * Pk[i][3];
                Pk[i][5] -= K0[5] * Pk[i][0] + K1[5] * Pk[i][3];
                float t0 = Pk[i][0] - (K0[0] * Pk[i][0] + K1[0] * Pk[i][3]);
                float t3 = Pk[i][3] - (K0[3] * Pk[i][0] + K1[3] * Pk[i][3]);
                Pk[i][0] = t0; Pk[i][3] = t3;
            }
        }
        if (lane == 0) {
            #pragma unroll
            for (int i = 0; i < 6; ++i)
                #pragma unroll
                for (int j = 0; j < 6; ++j) kf[180 + i * 6 + j] = Pk[i][j];
        }
    }

    // ---- LSTM weights, ROW-PERMUTED + exp2-folded scales ----
    s16x8 wih_h[8], whh_h[8];
    #pragma unroll
    for (int nt = 0; nt < 8; ++nt) {
        int G = nt >> 1, blk = nt & 1;
        float sc = (G == 2) ? T2L2E : NL2E;
        int base = (G * 32 + 8 * (e >> 2) + 4 * blk + (e & 3)) * NF + s * 8;
        frag_u ih_h, hh_h;
        #pragma unroll
        for (int q = 0; q < 4; ++q) {
            ih_h.u[q] = packbf2(sc * Wih[base + 2 * q], sc * Wih[base + 2 * q + 1]);
            hh_h.u[q] = packbf2(sc * Whh[base + 2 * q], sc * Whh[base + 2 * q + 1]);
        }
        wih_h[nt] = ih_h.v;
        whh_h[nt] = hh_h.v;
    }

    // bias fragments (register C-in), same row permutation + scales
    f32x4 biasF[8];
    #pragma unroll
    for (int nt = 0; nt < 8; ++nt) {
        int G = nt >> 1, blk = nt & 1;
        float sc = (G == 2) ? T2L2E : NL2E;
        int base = G * 32 + 8 * s + 4 * blk;
        f32x4 bi = *(const f32x4*)&bih[base];
        f32x4 bh = *(const f32x4*)&bhh[base];
        biasF[nt] = (bi + bh) * sc;
    }

    // feat-MFMA A-frags, row-permuted AND x(2log2e)
    s16x8 cfwA0, cfwA1;
    {
        frag_u fa0, fa1; fa0.v = (s16x8)0; fa1.v = (s16x8)0;
        if (s == 0) {
            int f0 = 8 * (e >> 2) + (e & 3);
            int f1 = f0 + 4;
            const float* w0 = cfW + f0 * 6;
            const float* w1 = cfW + f1 * 6;
            fa0.u[0] = packbf2(T2L2E * w0[0], T2L2E * w0[1]);
            fa0.u[1] = packbf2(T2L2E * w0[2], T2L2E * w0[3]);
            fa0.u[2] = packbf2(T2L2E * w0[4], T2L2E * w0[5]);
            fa0.u[3] = packbf2(T2L2E * cfb[f0], 0.0f);
            fa1.u[0] = packbf2(T2L2E * w1[0], T2L2E * w1[1]);
            fa1.u[1] = packbf2(T2L2E * w1[2], T2L2E * w1[3]);
            fa1.u[2] = packbf2(T2L2E * w1[4], T2L2E * w1[5]);
            fa1.u[3] = packbf2(T2L2E * cfb[f1], 0.0f);
        }
        cfwA0 = fa0.v; cfwA1 = fa1.v;
    }
    // cmd-MFMA A-frag: coW rows replicated 4x -> D[m=4s+r] = cmd_r in every lane
    s16x8 cmdA;
    {
        frag_u ca;
        const float* cp = coW + (e & 3) * NF + 8 * s;
        #pragma unroll
        for (int q = 0; q < 4; ++q)
            ca.u[q] = packbf2(cp[2 * q], cp[2 * q + 1]);
        cmdA = ca.v;
    }
    f32x4 cobC = {cob[0], cob[1], cob[2], cob[3]};

    // ---- Kalman state X, PACKED: Xa={X0,X3}, Xb={X1,X4}, Xc={X2,X5} ----
    const float2* hist2 = (const float2*)hist;
    float2 z0 = hist2[b];
    float2 z1 = hist2[B + b];
    f32x2 Xa = {z0.x, (z1.y - z0.y) / dt};
    f32x2 Xb = {(z1.x - z0.x) / dt, 0.0f};
    f32x2 Xc = {0.0f, 0.0f};

    f32x2 creg2[4];   // [2*blk+rp] = {cn(r=2rp), cn(r=2rp+1)}
    #pragma unroll
    for (int j = 0; j < 4; ++j) creg2[j] = (f32x2){0.0f, 0.0f};
    s16x8 ah_h = (s16x8)0;
    frag_u af_c;      // carried feat fragment (pipelined)

    __syncthreads();   // one-time: kf visible

    // feat front-end: xb pack + 2 MFMA + packed tanh -> af_c
    auto compute_feat = [&]() {
        frag_u xb;
        xb.u[0] = packbf2(Xa.x, Xb.x);            // X0,X1
        xb.u[1] = packbf2(Xc.x, Xa.y);            // X2,X3
        xb.u[2] = packbf2(Xb.y, Xc.y);            // X4,X5
        xb.u[3] = 0x00003f80u;                    // k6 = bf16(1.0)
        const f32x4 zc4 = {0.0f, 0.0f, 0.0f, 0.0f};
        f32x4 fp0 = __builtin_amdgcn_mfma_f32_16x16x32_bf16(cfwA0, xb.v, zc4, 0, 0, 0);
        f32x4 fp1 = __builtin_amdgcn_mfma_f32_16x16x32_bf16(cfwA1, xb.v, zc4, 0, 0, 0);
        auto tanh2p = [](float x0, float x1) -> f32x2 {
            f32x2 eg2 = {exp2b(x0), exp2b(x1)};
            f32x2 gp  = eg2 + 1.0f;
            f32x2 rd  = {frcp(gp.x), frcp(gp.y)};
            return (f32x2){1.0f, 1.0f} - 2.0f * rd;
        };
        { f32x2 t = tanh2p(fp0[0], fp0[1]); af_c.u[0] = packbf2(t.x, t.y); }
        { f32x2 t = tanh2p(fp0[2], fp0[3]); af_c.u[1] = packbf2(t.x, t.y); }
        { f32x2 t = tanh2p(fp1[0], fp1[1]); af_c.u[2] = packbf2(t.x, t.y); }
        { f32x2 t = tanh2p(fp1[2], fp1[3]); af_c.u[3] = packbf2(t.x, t.y); }
    };

    // gates + combine: consumes af_c + ah_h, updates creg2 + ah_h
    auto lstm_core = [&]() {
        f32x4 acc[8];
        #pragma unroll
        for (int nt = 0; nt < 8; ++nt) {
            acc[nt] = __builtin_amdgcn_mfma_f32_16x16x32_bf16(wih_h[nt], af_c.v, biasF[nt], 0, 0, 0);
            acc[nt] = __builtin_amdgcn_mfma_f32_16x16x32_bf16(whh_h[nt], ah_h, acc[nt], 0, 0, 0);
        }

        unsigned whx[2][2];
        #pragma unroll
        for (int blk = 0; blk < 2; ++blk) {
            #pragma unroll
            for (int rp = 0; rp < 2; ++rp) {
                int r0 = 2 * rp, r1 = 2 * rp + 1;
                f32x2 ei2 = {exp2b(acc[0 + blk][r0]), exp2b(acc[0 + blk][r1])};
                f32x2 ef2 = {exp2b(acc[2 + blk][r0]), exp2b(acc[2 + blk][r1])};
                f32x2 eg2 = {exp2b(acc[4 + blk][r0]), exp2b(acc[4 + blk][r1])};
                f32x2 eo2 = {exp2b(acc[6 + blk][r0]), exp2b(acc[6 + blk][r1])};
                f32x2 a2  = ef2 + 1.0f;
                f32x2 b2  = (ei2 + 1.0f) * (eg2 + 1.0f);
                f32x2 num = (eg2 - 1.0f) * a2 + creg2[2 * blk + rp] * b2;
                f32x2 den = a2 * b2;
                f32x2 rd  = {frcp(den.x), frcp(den.y)};
                f32x2 cn2 = num * rd;
                creg2[2 * blk + rp] = cn2;
                f32x2 cns = T2L2E * cn2;
                f32x2 ec2 = {exp2b(cns.x), exp2b(cns.y)};
                f32x2 d2  = (eo2 + 1.0f) * (ec2 + 1.0f);
                f32x2 rd2 = {frcp(d2.x), frcp(d2.y)};
                f32x2 hv2 = (ec2 - 1.0f) * rd2;
                whx[blk][rp] = packbf2(hv2.x, hv2.y);
            }
        }

        frag_u ahh;
        ahh.u[0] = whx[0][0];
        ahh.u[1] = whx[0][1];
        ahh.u[2] = whx[1][0];
        ahh.u[3] = whx[1][1];
        ah_h = ahh.v;
    };

    // ------------- history phase (feat pipelined one step ahead) -------------
    compute_feat();                       // feat(X_0)
    float2 zc = z1;
    #pragma unroll 1
    for (int t = 0; t < THIST; ++t) {
        int tn = (t + 2 < 16) ? (t + 2) : 15;
        float2 zn = hist2[(size_t)tn * B + b];
        f32x4 k0 = *(const f32x4*)&kf[t * 12];       // {K00,K03,K01,K04}
        f32x4 k1 = *(const f32x4*)&kf[t * 12 + 4];   // {K02,K05,K10,K13}
        f32x4 k2 = *(const f32x4*)&kf[t * 12 + 8];   // {K11,K14,K12,K15}

        lstm_core();                      // step t (uses feat(X_t))

        // X_{t+1} + feat(X_{t+1}) — independent of lstm_core; same block ->
        // scheduler interleaves their chains with combine's trans stalls.
        Xa = Xa + dt * Xb + hd * Xc;
        Xb = Xb + dt * Xc;
        float y0 = zc.x - Xa.x, y1 = zc.y - Xa.y;
        f32x2 kA0 = {k0[0], k0[1]}, kB0 = {k0[2], k0[3]}, kC0 = {k1[0], k1[1]};
        f32x2 kA1 = {k1[2], k1[3]}, kB1 = {k2[0], k2[1]}, kC1 = {k2[2], k2[3]};
        Xa = Xa + kA0 * y0 + kA1 * y1;
        Xb = Xb + kB0 * y0 + kB1 * y1;
        Xc = Xc + kC0 * y0 + kC1 * y1;
        zc = zn;
        compute_feat();                   // feat(X_{t+1}) for the next step
    }
    // af_c = feat(X_15) — pred step 0 consumes it.

    // P init; x/y blocks PACKED {x, y}
    f32x2 pxy00 = {kf[180], kf[201]}, pxy01 = {kf[181], kf[202]},
          pxy02 = {kf[182], kf[203]}, pxy11 = {kf[187], kf[208]},
          pxy12 = {kf[188], kf[209]}, pxy22 = {kf[194], kf[214]};
    float c00 = kf[183], c01 = kf[184], c02 = kf[185],
          c10 = kf[189], c11 = kf[190], c12 = kf[191],
          c20 = kf[195], c21 = kf[196], c22 = kf[197];
    const f32x2 gaP0 = {ga0, gb3}, gaP1 = {ga1, gb4}, gaP2 = {ga2, gb5};

    // P-update with a given cmd23 (identical arithmetic to R13)
    auto pupdate = [&](f32x2 cmd23) {
        f32x2 gsA = gaP0 * cmd23;
        f32x2 gsB = gaP1 * cmd23;
        f32x2 gsC = gaP2 * cmd23;
        {
            f32x2 r00 = pxy00 + dt * pxy01 + hd * pxy02;
            f32x2 r01 = pxy01 + dt * pxy11 + hd * pxy12;
            f32x2 r02 = pxy02 + dt * pxy12 + hd * pxy22;
            f32x2 r11 = pxy11 + dt * pxy12;
            f32x2 r12 = pxy12 + dt * pxy22;
            pxy00 = r00 + dt * r01 + hd * r02;
            pxy01 = r01 + dt * r02;
            pxy02 = r02;
            pxy11 = r11 + dt * r12;
            pxy12 = r12;
            pxy00 += gsA * gsA; pxy01 += gsA * gsB; pxy02 += gsA * gsC;
            pxy11 += gsB * gsB; pxy12 += gsB * gsC; pxy22 += gsC * gsC;
        }
        {
            float gs0 = gsA.x, gs1 = gsB.x, gs2 = gsC.x;
            float gs3 = gsA.y, gs4 = gsB.y, gs5 = gsC.y;
            float q00 = c00 + dt * c10 + hd * c20;
            float q01 = c01 + dt * c11 + hd * c21;
            float q02 = c02 + dt * c12 + hd * c22;
            float q10 = c10 + dt * c20;
            float q11 = c11 + dt * c21;
            float q12 = c12 + dt * c22;
            c00 = q00 + dt * q01 + hd * q02;
            c01 = q01 + dt * q02;
            c02 = q02;
            c10 = q10 + dt * q11 + hd * q12;
            c11 = q11 + dt * q12;
            c12 = q12;
            float n20 = c20 + dt * c21 + hd * c22;
            float n21 = c21 + dt * c22;
            c20 = n20; c21 = n21;
            c00 += gs0 * gs3; c01 += gs0 * gs4; c02 += gs0 * gs5;
            c10 += gs1 * gs3; c11 += gs1 * gs4; c12 += gs1 * gs5;
            c20 += gs2 * gs3; c21 += gs2 * gs4; c22 += gs2 * gs5;
        }
    };

    // ---------------- prediction phase (P/out rotated by one) ----------------
    // prologue: step 0 core + cmd + X-update + feat(for step 1)
    lstm_core();
    f32x4 cm = __builtin_amdgcn_mfma_f32_16x16x32_bf16(cmdA, ah_h, cobC, 0, 0, 0);
    {
        f32x2 cmdP = {cm[0], cm[1]};
        Xa = Xa + dt * Xb + hd * Xc + g0 * cmdP;
        Xb = Xb + dt * Xc + g1 * cmdP;
        Xc = Xc + g2 * cmdP;
    }
    f32x2 XoutSv = Xa;                     // {X0,X3} of step 0 (post-update)
    f32x2 cmdSv  = {cm[2], cm[3]};
    compute_feat();                        // feat for step 1

    #pragma unroll 1
    for (int tp = 1; tp < len_pred; ++tp) {
        lstm_core();                       // step tp (trans-heavy front)

        // step tp-1's P-update + output — independent of lstm_core above;
        // scheduler interleaves with its trans stalls.
        pupdate(cmdSv);
        {
            float sx = sqrtf(pxy00.x), sy = sqrtf(pxy00.y);
            float rho = c00 / (sx * sy);
            if (s == 0) {
                size_t o = ((size_t)(tp - 1) * B + b) * 5u;
                out[o + 0] = XoutSv.x;
                out[o + 1] = XoutSv.y;
                out[o + 2] = sx;
                out[o + 3] = sy;
                out[o + 4] = rho;
            }
        }

        cm = __builtin_amdgcn_mfma_f32_16x16x32_bf16(cmdA, ah_h, cobC, 0, 0, 0);
        f32x2 cmdP = {cm[0], cm[1]};
        Xa = Xa + dt * Xb + hd * Xc + g0 * cmdP;
        Xb = Xb + dt * Xc + g1 * cmdP;
        Xc = Xc + g2 * cmdP;
        XoutSv = Xa;
        cmdSv  = (f32x2){cm[2], cm[3]};
        if (tp < len_pred - 1) compute_feat();   // feat for step tp+1
    }

    // epilogue: last step's P-update + output
    pupdate(cmdSv);
    {
        float sx = sqrtf(pxy00.x), sy = sqrtf(pxy00.y);
        float rho = c00 / (sx * sy);
        if (s == 0) {
            size_t o = ((size_t)(len_pred - 1) * B + b) * 5u;
            out[o + 0] = XoutSv.x;
            out[o + 1] = XoutSv.y;
            out[o + 2] = sx;
            out[o + 3] = sy;
            out[o + 4] = rho;
        }
    }
}

extern "C" void kernel_launch(void* const* d_in, const int* in_sizes, int n_in,
                              void* d_out, int out_size, void* d_ws, size_t ws_size,
                              hipStream_t stream) {
    const int T = 16;
    const int B = in_sizes[0] / (2 * T);      // 32768
    const int len_pred = out_size / (5 * B);  // 25
    (void)d_ws; (void)ws_size; (void)n_in;

    const int grid = (B + EPB - 1) / EPB;     // one wave per 16 elements
    kalman_lstm<<<grid, BLK, 0, stream>>>(
        (const float*)d_in[0],  (const float*)d_in[1],  (const float*)d_in[2],
        (const float*)d_in[3],  (const float*)d_in[4],  (const float*)d_in[5],
        (const float*)d_in[6],  (const float*)d_in[7],  (const float*)d_in[8],
        (const float*)d_in[9],  (const float*)d_in[10], (const float*)d_in[11],
        (const float*)d_in[12], (const float*)d_in[13], (const float*)d_in[14],
        (const float*)d_in[15], (const float*)d_in[16], (const float*)d_in[17],
        (float*)d_out, B, len_pred);
}

// Round 16
// 175.263 us; speedup vs baseline: 1.0019x; 1.0019x over previous
//
#include <hip/hip_runtime.h>
#include <hip/hip_bf16.h>
#include <math.h>

#define BLK 64
#define EPB 16            // elements per block (one wave)
#define NF 32
#define THIST 15

typedef __attribute__((ext_vector_type(8))) short s16x8;  // 8 bf16 = 4 VGPRs
typedef __attribute__((ext_vector_type(4))) float f32x4;
typedef __attribute__((ext_vector_type(2))) float f32x2;  // -> v_pk_* f32 ops

union frag_u { s16x8 v; unsigned u[4]; };

__device__ __forceinline__ float frcp(float x) {
    return __builtin_amdgcn_rcpf(x);
}
__device__ __forceinline__ float fsqrt(float x) {
    return __builtin_amdgcn_sqrtf(x);
}
// raw v_exp_f32 via COMPILER BUILTIN (hazards handled; no OCML fixup).
__device__ __forceinline__ float exp2b(float x) {
    return __builtin_amdgcn_exp2f(x);
}
__device__ __forceinline__ unsigned packbf2(float x0, float x1) {
    __hip_bfloat162 b = __float22bfloat162_rn(float2{x0, x1});
    union { __hip_bfloat162 b; unsigned u; } c; c.b = b; return c.u;
}
// tanh for the uniform Riccati prologue only
__device__ __forceinline__ float tanhfe(float x) {
    float e = __expf(2.0f * x);
    return fmaf(-2.0f, frcp(e + 1.0f), 1.0f);
}

// P = F P F^T for the constant-accel F (dt=0.2), in place (uniform Riccati only)
__device__ __forceinline__ void fpft(float (&P)[6][6]) {
    const float dt = 0.2f, hd = 0.02f;
    #pragma unroll
    for (int j = 0; j < 6; ++j) {
        float a0 = P[0][j] + dt * P[1][j] + hd * P[2][j];
        float a1 = P[1][j] + dt * P[2][j];
        float a3 = P[3][j] + dt * P[4][j] + hd * P[5][j];
        float a4 = P[4][j] + dt * P[5][j];
        P[0][j] = a0; P[1][j] = a1; P[3][j] = a3; P[4][j] = a4;
    }
    #pragma unroll
    for (int i = 0; i < 6; ++i) {
        float a0 = P[i][0] + dt * P[i][1] + hd * P[i][2];
        float a1 = P[i][1] + dt * P[i][2];
        float a3 = P[i][3] + dt * P[i][4] + hd * P[i][5];
        float a4 = P[i][4] + dt * P[i][5];
        P[i][0] = a0; P[i][1] = a1; P[i][3] = a3; P[i][4] = a4;
    }
}

// ------------------------------- main kernel ---------------------------------
// R16 = R15 with the paired-rcp NaN fixed. R15 root cause: feat's exp2 arg is
// driven by UNBOUNDED X (velocity tails ~30 over 32k elems) -> 2^xp = inf ->
// paired rcp computes 0*inf = NaN (per-element rcp degraded gracefully).
// Fix: clamp xp <= 126 (2^126 finite; pair-product overflow then yields
// rr=0 -> r=0*finite=0 -> tanh=1 EXACTLY, same as the per-element path).
// cns <= 88 as pure NaN insurance (never active for realistic cn — R13
// passed unclamped). Gate-path pairs are weight-bounded (args <= 16.6), safe.
// Diagnostic retained: rcp 24 -> 12 per step; if dur ~90-93 trans mattered,
// if ~96 we are at the VALU-issue floor.
__global__ __launch_bounds__(BLK, 2)
void kalman_lstm(const float* __restrict__ hist,
                 const float* __restrict__ psx, const float* __restrict__ psy,
                 const float* __restrict__ vsx, const float* __restrict__ vsy,
                 const float* __restrict__ asx, const float* __restrict__ asy,
                 const float* __restrict__ jerk, const float* __restrict__ coefG,
                 const float* __restrict__ GRv,
                 const float* __restrict__ cfW, const float* __restrict__ cfb,
                 const float* __restrict__ Wih, const float* __restrict__ Whh,
                 const float* __restrict__ bih, const float* __restrict__ bhh,
                 const float* __restrict__ coW, const float* __restrict__ cob,
                 float* __restrict__ out, int B, int len_pred)
{
    __shared__ float kf[216];  // [t*12..+11]=K pairs (paired layout); [180..215]=P_hist

    const int lane = threadIdx.x;
    const int e = lane & 15;              // element slot (MFMA n-index / D col)
    const int s = lane >> 4;              // quad (k-slice / D row group)
    const int b = blockIdx.x * EPB + e;

    const float dt = 0.2f, hd = 0.02f;
    const float g0 = dt * dt * dt / 6.0f, g1 = 0.02f, g2 = dt;
    const float NL2E  = -1.4426950408889634f;   // -log2(e)
    const float T2L2E =  2.8853900817779268f;   // 2*log2(e)
    float ga0 = g0 * tanhf(coefG[0]);
    float ga1 = g1 * tanhf(coefG[1]);
    float ga2 = g2 * tanhf(coefG[2]);
    float gb3 = g0 * tanhf(coefG[3]);
    float gb4 = g1 * tanhf(coefG[4]);
    float gb5 = g2 * tanhf(coefG[5]);

    // ---- batch-uniform Kalman-gain recursion (verbatim math; lane0 writes) ----
    {
        float j0 = jerk[0], j1 = jerk[1];
        float gr0 = GRv[0], gr1 = GRv[1];
        float R00 = gr0 * gr0, R01 = gr0 * gr1, R11 = gr1 * gr1;
        float qa[3] = {ga0 * j0, ga1 * j0, ga2 * j0};
        float qb[3] = {gb3 * j1, gb4 * j1, gb5 * j1};

        float Pk[6][6];
        #pragma unroll
        for (int i = 0; i < 6; ++i)
            #pragma unroll
            for (int j = 0; j < 6; ++j) Pk[i][j] = 0.0f;
        { float v;
          v = psx[0]; Pk[0][0] = v * v;
          v = vsx[0]; Pk[1][1] = v * v;
          v = asx[0]; Pk[2][2] = v * v;
          v = psy[0]; Pk[3][3] = v * v;
          v = vsy[0]; Pk[4][4] = v * v;
          v = asy[0]; Pk[5][5] = v * v; }

        #pragma unroll 1
        for (int t = 0; t < THIST; ++t) {
            fpft(Pk);
            #pragma unroll
            for (int i = 0; i < 3; ++i)
                #pragma unroll
                for (int j = 0; j < 3; ++j) {
                    Pk[i][j]         += qa[i] * qa[j];
                    Pk[3 + i][3 + j] += qb[i] * qb[j];
                }
            float S00 = Pk[0][0] + R00;
            float S01 = Pk[0][3] + R01;
            float S11 = Pk[3][3] + R11;
            float idet = 1.0f / (S00 * S11 - S01 * S01);
            float i00 =  S11 * idet, i01 = -S01 * idet, i11 = S00 * idet;
            float K0[6], K1[6];
            #pragma unroll
            for (int i = 0; i < 6; ++i) {
                K0[i] = Pk[i][0] * i00 + Pk[i][3] * i01;
                K1[i] = Pk[i][0] * i01 + Pk[i][3] * i11;
            }
            if (lane == 0) {
                #pragma unroll
                for (int i = 0; i < 3; ++i) {
                    kf[t * 12 + 2 * i]     = K0[i];
                    kf[t * 12 + 2 * i + 1] = K0[3 + i];
                    kf[t * 12 + 6 + 2 * i]     = K1[i];
                    kf[t * 12 + 6 + 2 * i + 1] = K1[3 + i];
                }
            }
            #pragma unroll
            for (int i = 0; i < 6; ++i) {
                Pk[i][1] -= K0[1] * Pk[i][0] + K1[1] * Pk[i][3];
                Pk[i][2] -= K0[2] * Pk[i][0] + K1[2] * Pk[i][3];
                Pk[i][4] -= K0[4] * Pk[i][0] + K1[4] * Pk[i][3];
                Pk[i][5] -= K0[5] * Pk[i][0] + K1[5] * Pk[i][3];
                float t0 = Pk[i][0] - (K0[0] * Pk[i][0] + K1[0] * Pk[i][3]);
                float t3 = Pk[i][3] - (K0[3] * Pk[i][0] + K1[3] * Pk[i][3]);
                Pk[i][0] = t0; Pk[i][3] = t3;
            }
        }
        if (lane == 0) {
            #pragma unroll
            for (int i = 0; i < 6; ++i)
                #pragma unroll
                for (int j = 0; j < 6; ++j) kf[180 + i * 6 + j] = Pk[i][j];
        }
    }

    // ---- LSTM weights, ROW-PERMUTED + exp2-folded scales ----
    s16x8 wih_h[8], whh_h[8];
    #pragma unroll
    for (int nt = 0; nt < 8; ++nt) {
        int G = nt >> 1, blk = nt & 1;
        float sc = (G == 2) ? T2L2E : NL2E;
        int base = (G * 32 + 8 * (e >> 2) + 4 * blk + (e & 3)) * NF + s * 8;
        frag_u ih_h, hh_h;
        #pragma unroll
        for (int q = 0; q < 4; ++q) {
            ih_h.u[q] = packbf2(sc * Wih[base + 2 * q], sc * Wih[base + 2 * q + 1]);
            hh_h.u[q] = packbf2(sc * Whh[base + 2 * q], sc * Whh[base + 2 * q + 1]);
        }
        wih_h[nt] = ih_h.v;
        whh_h[nt] = hh_h.v;
    }

    // bias fragments (register C-in), same row permutation + scales
    f32x4 biasF[8];
    #pragma unroll
    for (int nt = 0; nt < 8; ++nt) {
        int G = nt >> 1, blk = nt & 1;
        float sc = (G == 2) ? T2L2E : NL2E;
        int base = G * 32 + 8 * s + 4 * blk;
        f32x4 bi = *(const f32x4*)&bih[base];
        f32x4 bh = *(const f32x4*)&bhh[base];
        biasF[nt] = (bi + bh) * sc;
    }

    // feat-MFMA A-frags, row-permuted AND x(2log2e)
    s16x8 cfwA0, cfwA1;
    {
        frag_u fa0, fa1; fa0.v = (s16x8)0; fa1.v = (s16x8)0;
        if (s == 0) {
            int f0 = 8 * (e >> 2) + (e & 3);
            int f1 = f0 + 4;
            const float* w0 = cfW + f0 * 6;
            const float* w1 = cfW + f1 * 6;
            fa0.u[0] = packbf2(T2L2E * w0[0], T2L2E * w0[1]);
            fa0.u[1] = packbf2(T2L2E * w0[2], T2L2E * w0[3]);
            fa0.u[2] = packbf2(T2L2E * w0[4], T2L2E * w0[5]);
            fa0.u[3] = packbf2(T2L2E * cfb[f0], 0.0f);
            fa1.u[0] = packbf2(T2L2E * w1[0], T2L2E * w1[1]);
            fa1.u[1] = packbf2(T2L2E * w1[2], T2L2E * w1[3]);
            fa1.u[2] = packbf2(T2L2E * w1[4], T2L2E * w1[5]);
            fa1.u[3] = packbf2(T2L2E * cfb[f1], 0.0f);
        }
        cfwA0 = fa0.v; cfwA1 = fa1.v;
    }
    // cmd-MFMA A-frag: coW rows replicated 4x -> D[m=4s+r] = cmd_r in every lane
    s16x8 cmdA;
    {
        frag_u ca;
        const float* cp = coW + (e & 3) * NF + 8 * s;
        #pragma unroll
        for (int q = 0; q < 4; ++q)
            ca.u[q] = packbf2(cp[2 * q], cp[2 * q + 1]);
        cmdA = ca.v;
    }
    f32x4 cobC = {cob[0], cob[1], cob[2], cob[3]};

    // ---- Kalman state X, PACKED: Xa={X0,X3}, Xb={X1,X4}, Xc={X2,X5} ----
    const float2* hist2 = (const float2*)hist;
    float2 z0 = hist2[b];
    float2 z1 = hist2[B + b];
    f32x2 Xa = {z0.x, (z1.y - z0.y) / dt};
    f32x2 Xb = {(z1.x - z0.x) / dt, 0.0f};
    f32x2 Xc = {0.0f, 0.0f};

    f32x2 creg2[4];   // [2*blk+rp] = {cn(r=2rp), cn(r=2rp+1)}
    #pragma unroll
    for (int j = 0; j < 4; ++j) creg2[j] = (f32x2){0.0f, 0.0f};
    s16x8 ah_h = (s16x8)0;
    frag_u af_c;      // carried feat fragment (pipelined)

    __syncthreads();   // one-time: kf visible

    // feat front-end: xb pack + 2 MFMA + paired-rcp tanh (clamped) -> af_c
    auto compute_feat = [&]() {
        frag_u xb;
        xb.u[0] = packbf2(Xa.x, Xb.x);            // X0,X1
        xb.u[1] = packbf2(Xc.x, Xa.y);            // X2,X3
        xb.u[2] = packbf2(Xb.y, Xc.y);            // X4,X5
        xb.u[3] = 0x00003f80u;                    // k6 = bf16(1.0)
        const f32x4 zc4 = {0.0f, 0.0f, 0.0f, 0.0f};
        f32x4 fp0 = __builtin_amdgcn_mfma_f32_16x16x32_bf16(cfwA0, xb.v, zc4, 0, 0, 0);
        f32x4 fp1 = __builtin_amdgcn_mfma_f32_16x16x32_bf16(cfwA1, xb.v, zc4, 0, 0, 0);
        // tanh pair with ONE rcp; args clamped <=126 so 2^x stays FINITE:
        // pair-product overflow then gives rr=0 -> r=0*finite=0 -> tanh=1
        // exactly (same as per-element saturation). No 0*inf possible.
        auto tanh2p = [](float x0, float x1) -> f32x2 {
            float e0 = exp2b(fminf(x0, 126.0f)), e1 = exp2b(fminf(x1, 126.0f));
            float d0 = e0 + 1.0f, d1 = e1 + 1.0f;
            float rr = frcp(d0 * d1);
            float r0 = rr * d1, r1 = rr * d0;
            return (f32x2){fmaf(-2.0f, r0, 1.0f), fmaf(-2.0f, r1, 1.0f)};
        };
        { f32x2 t = tanh2p(fp0[0], fp0[1]); af_c.u[0] = packbf2(t.x, t.y); }
        { f32x2 t = tanh2p(fp0[2], fp0[3]); af_c.u[1] = packbf2(t.x, t.y); }
        { f32x2 t = tanh2p(fp1[0], fp1[1]); af_c.u[2] = packbf2(t.x, t.y); }
        { f32x2 t = tanh2p(fp1[2], fp1[3]); af_c.u[3] = packbf2(t.x, t.y); }
    };

    // gates + combine: consumes af_c + ah_h, updates creg2 + ah_h.
    // Gate exp2 args are weight-bounded (<=16.6) -> no clamps needed there;
    // cns clamped <=88 as NaN insurance (d2 <= 2^105 finite).
    auto lstm_core = [&]() {
        f32x4 acc[8];
        #pragma unroll
        for (int nt = 0; nt < 8; ++nt) {
            acc[nt] = __builtin_amdgcn_mfma_f32_16x16x32_bf16(wih_h[nt], af_c.v, biasF[nt], 0, 0, 0);
            acc[nt] = __builtin_amdgcn_mfma_f32_16x16x32_bf16(whh_h[nt], ah_h, acc[nt], 0, 0, 0);
        }

        unsigned whx[2][2];
        #pragma unroll
        for (int blk = 0; blk < 2; ++blk) {
            #pragma unroll
            for (int rp = 0; rp < 2; ++rp) {
                int r0 = 2 * rp, r1 = 2 * rp + 1;
                f32x2 ei2 = {exp2b(acc[0 + blk][r0]), exp2b(acc[0 + blk][r1])};
                f32x2 ef2 = {exp2b(acc[2 + blk][r0]), exp2b(acc[2 + blk][r1])};
                f32x2 eg2 = {exp2b(acc[4 + blk][r0]), exp2b(acc[4 + blk][r1])};
                f32x2 eo2 = {exp2b(acc[6 + blk][r0]), exp2b(acc[6 + blk][r1])};
                f32x2 a2  = ef2 + 1.0f;
                f32x2 b2  = (ei2 + 1.0f) * (eg2 + 1.0f);
                f32x2 num = (eg2 - 1.0f) * a2 + creg2[2 * blk + rp] * b2;
                f32x2 den = a2 * b2;
                // paired rcp: one trans for both elements (den <= 2^67 finite)
                float rr  = frcp(den.x * den.y);
                f32x2 rd  = {rr * den.y, rr * den.x};
                f32x2 cn2 = num * rd;
                creg2[2 * blk + rp] = cn2;
                f32x2 cns = {fminf(T2L2E * cn2.x, 88.0f),
                             fminf(T2L2E * cn2.y, 88.0f)};
                f32x2 ec2 = {exp2b(cns.x), exp2b(cns.y)};
                f32x2 d2  = (eo2 + 1.0f) * (ec2 + 1.0f);
                float rr2 = frcp(d2.x * d2.y);
                f32x2 rd2 = {rr2 * d2.y, rr2 * d2.x};
                f32x2 hv2 = (ec2 - 1.0f) * rd2;
                whx[blk][rp] = packbf2(hv2.x, hv2.y);
            }
        }

        frag_u ahh;
        ahh.u[0] = whx[0][0];
        ahh.u[1] = whx[0][1];
        ahh.u[2] = whx[1][0];
        ahh.u[3] = whx[1][1];
        ah_h = ahh.v;
    };

    // ------------- history phase (feat pipelined one step ahead) -------------
    compute_feat();                       // feat(X_0)
    float2 zc = z1;
    #pragma unroll 1
    for (int t = 0; t < THIST; ++t) {
        int tn = (t + 2 < 16) ? (t + 2) : 15;
        float2 zn = hist2[(size_t)tn * B + b];
        f32x4 k0 = *(const f32x4*)&kf[t * 12];       // {K00,K03,K01,K04}
        f32x4 k1 = *(const f32x4*)&kf[t * 12 + 4];   // {K02,K05,K10,K13}
        f32x4 k2 = *(const f32x4*)&kf[t * 12 + 8];   // {K11,K14,K12,K15}

        lstm_core();                      // step t (uses feat(X_t))

        Xa = Xa + dt * Xb + hd * Xc;
        Xb = Xb + dt * Xc;
        float y0 = zc.x - Xa.x, y1 = zc.y - Xa.y;
        f32x2 kA0 = {k0[0], k0[1]}, kB0 = {k0[2], k0[3]}, kC0 = {k1[0], k1[1]};
        f32x2 kA1 = {k1[2], k1[3]}, kB1 = {k2[0], k2[1]}, kC1 = {k2[2], k2[3]};
        Xa = Xa + kA0 * y0 + kA1 * y1;
        Xb = Xb + kB0 * y0 + kB1 * y1;
        Xc = Xc + kC0 * y0 + kC1 * y1;
        zc = zn;
        compute_feat();                   // feat(X_{t+1}) for the next step
    }

    // P init; x/y blocks PACKED {x, y}
    f32x2 pxy00 = {kf[180], kf[201]}, pxy01 = {kf[181], kf[202]},
          pxy02 = {kf[182], kf[203]}, pxy11 = {kf[187], kf[208]},
          pxy12 = {kf[188], kf[209]}, pxy22 = {kf[194], kf[214]};
    float c00 = kf[183], c01 = kf[184], c02 = kf[185],
          c10 = kf[189], c11 = kf[190], c12 = kf[191],
          c20 = kf[195], c21 = kf[196], c22 = kf[197];
    const f32x2 gaP0 = {ga0, gb3}, gaP1 = {ga1, gb4}, gaP2 = {ga2, gb5};

    auto pupdate = [&](f32x2 cmd23) {
        f32x2 gsA = gaP0 * cmd23;
        f32x2 gsB = gaP1 * cmd23;
        f32x2 gsC = gaP2 * cmd23;
        {
            f32x2 r00 = pxy00 + dt * pxy01 + hd * pxy02;
            f32x2 r01 = pxy01 + dt * pxy11 + hd * pxy12;
            f32x2 r02 = pxy02 + dt * pxy12 + hd * pxy22;
            f32x2 r11 = pxy11 + dt * pxy12;
            f32x2 r12 = pxy12 + dt * pxy22;
            pxy00 = r00 + dt * r01 + hd * r02;
            pxy01 = r01 + dt * r02;
            pxy02 = r02;
            pxy11 = r11 + dt * r12;
            pxy12 = r12;
            pxy00 += gsA * gsA; pxy01 += gsA * gsB; pxy02 += gsA * gsC;
            pxy11 += gsB * gsB; pxy12 += gsB * gsC; pxy22 += gsC * gsC;
        }
        {
            float gs0 = gsA.x, gs1 = gsB.x, gs2 = gsC.x;
            float gs3 = gsA.y, gs4 = gsB.y, gs5 = gsC.y;
            float q00 = c00 + dt * c10 + hd * c20;
            float q01 = c01 + dt * c11 + hd * c21;
            float q02 = c02 + dt * c12 + hd * c22;
            float q10 = c10 + dt * c20;
            float q11 = c11 + dt * c21;
            float q12 = c12 + dt * c22;
            c00 = q00 + dt * q01 + hd * q02;
            c01 = q01 + dt * q02;
            c02 = q02;
            c10 = q10 + dt * q11 + hd * q12;
            c11 = q11 + dt * q12;
            c12 = q12;
            float n20 = c20 + dt * c21 + hd * c22;
            float n21 = c21 + dt * c22;
            c20 = n20; c21 = n21;
            c00 += gs0 * gs3; c01 += gs0 * gs4; c02 += gs0 * gs5;
            c10 += gs1 * gs3; c11 += gs1 * gs4; c12 += gs1 * gs5;
            c20 += gs2 * gs3; c21 += gs2 * gs4; c22 += gs2 * gs5;
        }
    };

    // ---------------- prediction phase (P/out rotated by one) ----------------
    lstm_core();
    f32x4 cm = __builtin_amdgcn_mfma_f32_16x16x32_bf16(cmdA, ah_h, cobC, 0, 0, 0);
    {
        f32x2 cmdP = {cm[0], cm[1]};
        Xa = Xa + dt * Xb + hd * Xc + g0 * cmdP;
        Xb = Xb + dt * Xc + g1 * cmdP;
        Xc = Xc + g2 * cmdP;
    }
    f32x2 XoutSv = Xa;                     // {X0,X3} of step 0 (post-update)
    f32x2 cmdSv  = {cm[2], cm[3]};
    compute_feat();                        // feat for step 1

    float* op = out + (size_t)b * 5u;      // output cursor (incremented by 5B)
    const size_t ostep = (size_t)B * 5u;

    #pragma unroll 1
    for (int tp = 1; tp < len_pred; ++tp) {
        lstm_core();                       // step tp

        // step tp-1's P-update + output
        pupdate(cmdSv);
        {
            float sx = fsqrt(pxy00.x), sy = fsqrt(pxy00.y);
            float rho = c00 * frcp(sx * sy);
            if (s == 0) {
                op[0] = XoutSv.x;
                op[1] = XoutSv.y;
                op[2] = sx;
                op[3] = sy;
                op[4] = rho;
            }
            op += ostep;
        }

        cm = __builtin_amdgcn_mfma_f32_16x16x32_bf16(cmdA, ah_h, cobC, 0, 0, 0);
        f32x2 cmdP = {cm[0], cm[1]};
        Xa = Xa + dt * Xb + hd * Xc + g0 * cmdP;
        Xb = Xb + dt * Xc + g1 * cmdP;
        Xc = Xc + g2 * cmdP;
        XoutSv = Xa;
        cmdSv  = (f32x2){cm[2], cm[3]};
        if (tp < len_pred - 1) compute_feat();   // feat for step tp+1
    }

    // epilogue: last step's P-update + output
    pupdate(cmdSv);
    {
        float sx = fsqrt(pxy00.x), sy = fsqrt(pxy00.y);
        float rho = c00 * frcp(sx * sy);
        if (s == 0) {
            op[0] = XoutSv.x;
            op[1] = XoutSv.y;
            op[2] = sx;
            op[3] = sy;
            op[4] = rho;
        }
    }
}

extern "C" void kernel_launch(void* const* d_in, const int* in_sizes, int n_in,
                              void* d_out, int out_size, void* d_ws, size_t ws_size,
                              hipStream_t stream) {
    const int T = 16;
    const int B = in_sizes[0] / (2 * T);      // 32768
    const int len_pred = out_size / (5 * B);  // 25
    (void)d_ws; (void)ws_size; (void)n_in;

    const int grid = (B + EPB - 1) / EPB;     // one wave per 16 elements
    kalman_lstm<<<grid, BLK, 0, stream>>>(
        (const float*)d_in[0],  (const float*)d_in[1],  (const float*)d_in[2],
        (const float*)d_in[3],  (const float*)d_in[4],  (const float*)d_in[5],
        (const float*)d_in[6],  (const float*)d_in[7],  (const float*)d_in[8],
        (const float*)d_in[9],  (const float*)d_in[10], (const float*)d_in[11],
        (const float*)d_in[12], (const float*)d_in[13], (const float*)d_in[14],
        (const float*)d_in[15], (const float*)d_in[16], (const float*)d_in[17],
        (float*)d_out, B, len_pred);
}